// Round 1
// baseline (646.023 us; speedup 1.0000x reference)
//
#include <hip/hip_runtime.h>
#include <hip/hip_bf16.h>

#define N_FEAT 128
#define N_HID  128
#define N_CLASS 40

// ---------------------------------------------------------------------------
// CSR build: count degrees
// ---------------------------------------------------------------------------
__global__ void k_count(const int* __restrict__ dst, int* __restrict__ cnt, int E) {
    int e = blockIdx.x * blockDim.x + threadIdx.x;
    if (e < E) atomicAdd(&cnt[dst[e]], 1);
}

// ---------------------------------------------------------------------------
// Single-block exclusive prefix scan over cnt[0..n) -> off[0..n], cur copy.
// Shuffle-based wave scan + cross-wave LDS; 4 barriers per 1024-chunk.
// ---------------------------------------------------------------------------
__global__ __launch_bounds__(1024) void k_scan(const int* __restrict__ cnt,
                                               int* __restrict__ off,
                                               int* __restrict__ cur, int n) {
    const int tid = threadIdx.x;
    const int lane = tid & 63;
    const int wid = tid >> 6;              // 16 waves
    __shared__ int wsum[16];
    __shared__ int carry;
    if (tid == 0) carry = 0;
    __syncthreads();
    for (int base = 0; base < n; base += 1024) {
        int i = base + tid;
        int v = (i < n) ? cnt[i] : 0;
        int inc = v;
        #pragma unroll
        for (int s = 1; s < 64; s <<= 1) {
            int t = __shfl_up(inc, s);
            if (lane >= s) inc += t;
        }
        if (lane == 63) wsum[wid] = inc;
        __syncthreads();
        if (wid == 0) {
            int w = (lane < 16) ? wsum[lane] : 0;
            #pragma unroll
            for (int s = 1; s < 16; s <<= 1) {
                int t = __shfl_up(w, s);
                if (lane >= s) w += t;
            }
            if (lane < 16) wsum[lane] = w;  // inclusive wave sums
        }
        __syncthreads();
        int wbase = (wid > 0) ? wsum[wid - 1] : 0;
        int exc = carry + wbase + inc - v;  // exclusive prefix
        if (i < n) { off[i] = exc; cur[i] = exc; }
        int chunk_total = wsum[15];
        __syncthreads();                    // everyone done reading carry/wsum
        if (tid == 0) carry += chunk_total;
        __syncthreads();
    }
    if (tid == 0) off[n] = carry;           // == E
}

// ---------------------------------------------------------------------------
// CSR build: scatter src ids into per-dst buckets
// ---------------------------------------------------------------------------
__global__ void k_fill(const int* __restrict__ src, const int* __restrict__ dst,
                       int* __restrict__ cur, int* __restrict__ srt, int E) {
    int e = blockIdx.x * blockDim.x + threadIdx.x;
    if (e < E) {
        int p = atomicAdd(&cur[dst[e]], 1);
        srt[p] = src[e];
    }
}

// ---------------------------------------------------------------------------
// Mean aggregation: one wave per node, lane holds 2 features (float2).
// out[n,:] = mean over neighbors s of feat[s,:]   (0 if no neighbors)
// ---------------------------------------------------------------------------
__global__ __launch_bounds__(256) void k_agg(const float* __restrict__ feat,
                                             const int* __restrict__ srt,
                                             const int* __restrict__ off,
                                             const int* __restrict__ cnt,
                                             float* __restrict__ out, int n_nodes) {
    int wave = (blockIdx.x * blockDim.x + threadIdx.x) >> 6;
    int lane = threadIdx.x & 63;
    if (wave >= n_nodes) return;
    int beg = off[wave];
    int end = off[wave + 1];
    float2 acc = make_float2(0.f, 0.f);
    for (int e = beg; e < end; ++e) {
        int s = srt[e];
        const float2* row = (const float2*)(feat + (size_t)s * N_FEAT);
        float2 v = row[lane];
        acc.x += v.x;
        acc.y += v.y;
    }
    int c = cnt[wave];
    float inv = 1.0f / (float)(c > 1 ? c : 1);
    acc.x *= inv;
    acc.y *= inv;
    ((float2*)(out + (size_t)wave * N_FEAT))[lane] = acc;
}

// ---------------------------------------------------------------------------
// Layer 1: h[n, c0+c] = relu( sum_k agg[n,k]*Wl[k,c0+c] + x[n,k]*Wr[k,c0+c] + b[c0+c] )
// Thread = node; 64 outputs per pass (blockIdx.y selects half).
// Weight addresses are thread-uniform -> scalar s_loads, one SGPR per v_fma.
// ---------------------------------------------------------------------------
__global__ __launch_bounds__(256) void k_gemm1(const float* __restrict__ agg,
                                               const float* __restrict__ x,
                                               const float* __restrict__ Wl,
                                               const float* __restrict__ Wr,
                                               const float* __restrict__ b,
                                               float* __restrict__ h, int n_nodes) {
    int n = blockIdx.x * 256 + threadIdx.x;
    int c0 = blockIdx.y * 64;
    if (n >= n_nodes) return;
    float acc[64];
    #pragma unroll
    for (int c = 0; c < 64; ++c) acc[c] = b[c0 + c];
    const float4* arow = (const float4*)(agg + (size_t)n * N_FEAT);
    const float4* xrow = (const float4*)(x + (size_t)n * N_FEAT);
    for (int k4 = 0; k4 < N_FEAT / 4; ++k4) {
        float4 a4 = arow[k4];
        float4 x4 = xrow[k4];
        #pragma unroll
        for (int kk = 0; kk < 4; ++kk) {
            float av = (&a4.x)[kk];
            float xv = (&x4.x)[kk];
            int k = k4 * 4 + kk;
            const float* wlrow = Wl + (size_t)k * N_HID + c0;
            const float* wrrow = Wr + (size_t)k * N_HID + c0;
            #pragma unroll
            for (int c = 0; c < 64; ++c)
                acc[c] += av * wlrow[c] + xv * wrrow[c];
        }
    }
    float4* hrow = (float4*)(h + (size_t)n * N_HID + c0);
    #pragma unroll
    for (int c4 = 0; c4 < 16; ++c4) {
        float4 o;
        o.x = fmaxf(acc[c4 * 4 + 0], 0.f);
        o.y = fmaxf(acc[c4 * 4 + 1], 0.f);
        o.z = fmaxf(acc[c4 * 4 + 2], 0.f);
        o.w = fmaxf(acc[c4 * 4 + 3], 0.f);
        hrow[c4] = o;
    }
}

// ---------------------------------------------------------------------------
// Layer 2: out[n, c] = sum_k agg2[n,k]*Wl2[k,c] + h[n,k]*Wr2[k,c] + b2[c]
// Thread = node, 40 outputs. out rows are 160 B -> float4-aligned.
// ---------------------------------------------------------------------------
__global__ __launch_bounds__(256) void k_gemm2(const float* __restrict__ agg2,
                                               const float* __restrict__ h,
                                               const float* __restrict__ Wl,
                                               const float* __restrict__ Wr,
                                               const float* __restrict__ b,
                                               float* __restrict__ outp, int n_nodes) {
    int n = blockIdx.x * 256 + threadIdx.x;
    if (n >= n_nodes) return;
    float acc[N_CLASS];
    #pragma unroll
    for (int c = 0; c < N_CLASS; ++c) acc[c] = b[c];
    const float4* arow = (const float4*)(agg2 + (size_t)n * N_HID);
    const float4* hrow = (const float4*)(h + (size_t)n * N_HID);
    for (int k4 = 0; k4 < N_HID / 4; ++k4) {
        float4 a4 = arow[k4];
        float4 h4 = hrow[k4];
        #pragma unroll
        for (int kk = 0; kk < 4; ++kk) {
            float av = (&a4.x)[kk];
            float hv = (&h4.x)[kk];
            int k = k4 * 4 + kk;
            const float* wlrow = Wl + (size_t)k * N_CLASS;
            const float* wrrow = Wr + (size_t)k * N_CLASS;
            #pragma unroll
            for (int c = 0; c < N_CLASS; ++c)
                acc[c] += av * wlrow[c] + hv * wrrow[c];
        }
    }
    float4* orow = (float4*)(outp + (size_t)n * N_CLASS);
    #pragma unroll
    for (int c4 = 0; c4 < N_CLASS / 4; ++c4) {
        float4 o;
        o.x = acc[c4 * 4 + 0];
        o.y = acc[c4 * 4 + 1];
        o.z = acc[c4 * 4 + 2];
        o.w = acc[c4 * 4 + 3];
        orow[c4] = o;
    }
}

extern "C" void kernel_launch(void* const* d_in, const int* in_sizes, int n_in,
                              void* d_out, int out_size, void* d_ws, size_t ws_size,
                              hipStream_t stream) {
    const float* x   = (const float*)d_in[0];
    const int*   ei  = (const int*)d_in[1];   // [2][E] int32: row0=src, row1=dst
    const float* Wl1 = (const float*)d_in[2];
    const float* Wr1 = (const float*)d_in[3];
    const float* b1  = (const float*)d_in[4];
    const float* Wl2 = (const float*)d_in[5];
    const float* Wr2 = (const float*)d_in[6];
    const float* b2  = (const float*)d_in[7];
    float* out = (float*)d_out;

    const int N = in_sizes[0] / N_FEAT;       // 50000
    const int E = in_sizes[1] / 2;            // 800000
    const int* src = ei;
    const int* dst = ei + E;

    // Workspace carve (all recomputed every call; ws is poisoned between calls)
    float* agg = (float*)d_ws;                       // N*128 fp32 (reused for agg2)
    float* h   = agg + (size_t)N * N_FEAT;           // N*128 fp32
    int*   cnt = (int*)(h + (size_t)N * N_HID);      // N
    int*   off = cnt + N;                            // N+1
    int*   cur = off + N + 1;                        // N
    int*   srt = cur + N;                            // E

    hipMemsetAsync(cnt, 0, (size_t)N * sizeof(int), stream);

    const int TB = 256;
    int eblocks = (E + TB - 1) / TB;
    k_count<<<eblocks, TB, 0, stream>>>(dst, cnt, E);
    k_scan<<<1, 1024, 0, stream>>>(cnt, off, cur, N);
    k_fill<<<eblocks, TB, 0, stream>>>(src, dst, cur, srt, E);

    int aggblocks = (N * 64 + TB - 1) / TB;   // one wave (64 lanes) per node
    int nblocks = (N + TB - 1) / TB;

    // Layer 1
    k_agg<<<aggblocks, TB, 0, stream>>>(x, srt, off, cnt, agg, N);
    k_gemm1<<<dim3(nblocks, 2), TB, 0, stream>>>(agg, x, Wl1, Wr1, b1, h, N);

    // Layer 2
    k_agg<<<aggblocks, TB, 0, stream>>>(h, srt, off, cnt, agg, N);
    k_gemm2<<<nblocks, TB, 0, stream>>>(agg, h, Wl2, Wr2, b2, out, N);
}

// Round 2
// 635.887 us; speedup vs baseline: 1.0159x; 1.0159x over previous
//
#include <hip/hip_runtime.h>
#include <hip/hip_bf16.h>

#define N_FEAT 128
#define N_HID  128
#define N_CLASS 40

// ---------------------------------------------------------------------------
// CSR build: count degrees
// ---------------------------------------------------------------------------
__global__ void k_count(const int* __restrict__ dst, int* __restrict__ cnt, int E) {
    int e = blockIdx.x * blockDim.x + threadIdx.x;
    if (e < E) atomicAdd(&cnt[dst[e]], 1);
}

// ---------------------------------------------------------------------------
// Single-block exclusive prefix scan over cnt[0..n) -> off[0..n], cur copy.
// ---------------------------------------------------------------------------
__global__ __launch_bounds__(1024) void k_scan(const int* __restrict__ cnt,
                                               int* __restrict__ off,
                                               int* __restrict__ cur, int n) {
    const int tid = threadIdx.x;
    const int lane = tid & 63;
    const int wid = tid >> 6;              // 16 waves
    __shared__ int wsum[16];
    __shared__ int carry;
    if (tid == 0) carry = 0;
    __syncthreads();
    for (int base = 0; base < n; base += 1024) {
        int i = base + tid;
        int v = (i < n) ? cnt[i] : 0;
        int inc = v;
        #pragma unroll
        for (int s = 1; s < 64; s <<= 1) {
            int t = __shfl_up(inc, s);
            if (lane >= s) inc += t;
        }
        if (lane == 63) wsum[wid] = inc;
        __syncthreads();
        if (wid == 0) {
            int w = (lane < 16) ? wsum[lane] : 0;
            #pragma unroll
            for (int s = 1; s < 16; s <<= 1) {
                int t = __shfl_up(w, s);
                if (lane >= s) w += t;
            }
            if (lane < 16) wsum[lane] = w;  // inclusive wave sums
        }
        __syncthreads();
        int wbase = (wid > 0) ? wsum[wid - 1] : 0;
        int exc = carry + wbase + inc - v;  // exclusive prefix
        if (i < n) { off[i] = exc; cur[i] = exc; }
        int chunk_total = wsum[15];
        __syncthreads();
        if (tid == 0) carry += chunk_total;
        __syncthreads();
    }
    if (tid == 0) off[n] = carry;           // == E
}

// ---------------------------------------------------------------------------
// CSR build: scatter src ids into per-dst buckets
// ---------------------------------------------------------------------------
__global__ void k_fill(const int* __restrict__ src, const int* __restrict__ dst,
                       int* __restrict__ cur, int* __restrict__ srt, int E) {
    int e = blockIdx.x * blockDim.x + threadIdx.x;
    if (e < E) {
        int p = atomicAdd(&cur[dst[e]], 1);
        srt[p] = src[e];
    }
}

// ---------------------------------------------------------------------------
// Mean aggregation: one wave per node, lane holds 2 features (float2).
// ---------------------------------------------------------------------------
__global__ __launch_bounds__(256) void k_agg(const float* __restrict__ feat,
                                             const int* __restrict__ srt,
                                             const int* __restrict__ off,
                                             const int* __restrict__ cnt,
                                             float* __restrict__ out, int n_nodes) {
    int wave = (blockIdx.x * blockDim.x + threadIdx.x) >> 6;
    int lane = threadIdx.x & 63;
    if (wave >= n_nodes) return;
    int beg = off[wave];
    int end = off[wave + 1];
    float2 acc = make_float2(0.f, 0.f);
    for (int e = beg; e < end; ++e) {
        int s = srt[e];
        const float2* row = (const float2*)(feat + (size_t)s * N_FEAT);
        float2 v = row[lane];
        acc.x += v.x;
        acc.y += v.y;
    }
    int c = cnt[wave];
    float inv = 1.0f / (float)(c > 1 ? c : 1);
    acc.x *= inv;
    acc.y *= inv;
    ((float2*)(out + (size_t)wave * N_FEAT))[lane] = acc;
}

// ---------------------------------------------------------------------------
// Layer 1: h = relu(agg@Wl + x@Wr + b). Thread = node, 64 outputs per y-block.
// __launch_bounds__(256, 2): min 2 waves/EU -> VGPR cap 256, so acc[64] stays
// in registers (R1 profile showed VGPR=48 => acc spilled to scratch, FETCH
// 326 MB vs ~100 MB legit -> spill traffic dominated).
// ---------------------------------------------------------------------------
__global__ __launch_bounds__(256, 2) void k_gemm1(const float* __restrict__ agg,
                                                  const float* __restrict__ x,
                                                  const float* __restrict__ Wl,
                                                  const float* __restrict__ Wr,
                                                  const float* __restrict__ b,
                                                  float* __restrict__ h, int n_nodes) {
    int n = blockIdx.x * 256 + threadIdx.x;
    int c0 = blockIdx.y * 64;
    if (n >= n_nodes) return;
    float acc[64];
    #pragma unroll
    for (int c = 0; c < 64; ++c) acc[c] = b[c0 + c];
    const float4* arow = (const float4*)(agg + (size_t)n * N_FEAT);
    const float4* xrow = (const float4*)(x + (size_t)n * N_FEAT);
    for (int k4 = 0; k4 < N_FEAT / 4; ++k4) {
        float4 a4 = arow[k4];
        float4 x4 = xrow[k4];
        const float* wl = Wl + (size_t)(k4 * 4) * N_HID + c0;
        const float* wr = Wr + (size_t)(k4 * 4) * N_HID + c0;
        #pragma unroll
        for (int c = 0; c < 64; ++c)
            acc[c] += a4.x * wl[c] + x4.x * wr[c];
        wl += N_HID; wr += N_HID;
        #pragma unroll
        for (int c = 0; c < 64; ++c)
            acc[c] += a4.y * wl[c] + x4.y * wr[c];
        wl += N_HID; wr += N_HID;
        #pragma unroll
        for (int c = 0; c < 64; ++c)
            acc[c] += a4.z * wl[c] + x4.z * wr[c];
        wl += N_HID; wr += N_HID;
        #pragma unroll
        for (int c = 0; c < 64; ++c)
            acc[c] += a4.w * wl[c] + x4.w * wr[c];
    }
    float4* hrow = (float4*)(h + (size_t)n * N_HID + c0);
    #pragma unroll
    for (int c4 = 0; c4 < 16; ++c4) {
        float4 o;
        o.x = fmaxf(acc[c4 * 4 + 0], 0.f);
        o.y = fmaxf(acc[c4 * 4 + 1], 0.f);
        o.z = fmaxf(acc[c4 * 4 + 2], 0.f);
        o.w = fmaxf(acc[c4 * 4 + 3], 0.f);
        hrow[c4] = o;
    }
}

// ---------------------------------------------------------------------------
// Layer 2: out = agg2@Wl2 + h@Wr2 + b2. Thread = node, 40 outputs.
// ---------------------------------------------------------------------------
__global__ __launch_bounds__(256, 2) void k_gemm2(const float* __restrict__ agg2,
                                                  const float* __restrict__ h,
                                                  const float* __restrict__ Wl,
                                                  const float* __restrict__ Wr,
                                                  const float* __restrict__ b,
                                                  float* __restrict__ outp, int n_nodes) {
    int n = blockIdx.x * 256 + threadIdx.x;
    if (n >= n_nodes) return;
    float acc[N_CLASS];
    #pragma unroll
    for (int c = 0; c < N_CLASS; ++c) acc[c] = b[c];
    const float4* arow = (const float4*)(agg2 + (size_t)n * N_HID);
    const float4* hrow = (const float4*)(h + (size_t)n * N_HID);
    for (int k4 = 0; k4 < N_HID / 4; ++k4) {
        float4 a4 = arow[k4];
        float4 h4 = hrow[k4];
        const float* wl = Wl + (size_t)(k4 * 4) * N_CLASS;
        const float* wr = Wr + (size_t)(k4 * 4) * N_CLASS;
        #pragma unroll
        for (int c = 0; c < N_CLASS; ++c)
            acc[c] += a4.x * wl[c] + h4.x * wr[c];
        wl += N_CLASS; wr += N_CLASS;
        #pragma unroll
        for (int c = 0; c < N_CLASS; ++c)
            acc[c] += a4.y * wl[c] + h4.y * wr[c];
        wl += N_CLASS; wr += N_CLASS;
        #pragma unroll
        for (int c = 0; c < N_CLASS; ++c)
            acc[c] += a4.z * wl[c] + h4.z * wr[c];
        wl += N_CLASS; wr += N_CLASS;
        #pragma unroll
        for (int c = 0; c < N_CLASS; ++c)
            acc[c] += a4.w * wl[c] + h4.w * wr[c];
    }
    float4* orow = (float4*)(outp + (size_t)n * N_CLASS);
    #pragma unroll
    for (int c4 = 0; c4 < N_CLASS / 4; ++c4) {
        float4 o;
        o.x = acc[c4 * 4 + 0];
        o.y = acc[c4 * 4 + 1];
        o.z = acc[c4 * 4 + 2];
        o.w = acc[c4 * 4 + 3];
        orow[c4] = o;
    }
}

extern "C" void kernel_launch(void* const* d_in, const int* in_sizes, int n_in,
                              void* d_out, int out_size, void* d_ws, size_t ws_size,
                              hipStream_t stream) {
    const float* x   = (const float*)d_in[0];
    const int*   ei  = (const int*)d_in[1];   // [2][E] int32: row0=src, row1=dst
    const float* Wl1 = (const float*)d_in[2];
    const float* Wr1 = (const float*)d_in[3];
    const float* b1  = (const float*)d_in[4];
    const float* Wl2 = (const float*)d_in[5];
    const float* Wr2 = (const float*)d_in[6];
    const float* b2  = (const float*)d_in[7];
    float* out = (float*)d_out;

    const int N = in_sizes[0] / N_FEAT;       // 50000
    const int E = in_sizes[1] / 2;            // 800000
    const int* src = ei;
    const int* dst = ei + E;

    float* agg = (float*)d_ws;                       // N*128 fp32 (reused for agg2)
    float* h   = agg + (size_t)N * N_FEAT;           // N*128 fp32
    int*   cnt = (int*)(h + (size_t)N * N_HID);      // N
    int*   off = cnt + N;                            // N+1
    int*   cur = off + N + 1;                        // N
    int*   srt = cur + N;                            // E

    hipMemsetAsync(cnt, 0, (size_t)N * sizeof(int), stream);

    const int TB = 256;
    int eblocks = (E + TB - 1) / TB;
    k_count<<<eblocks, TB, 0, stream>>>(dst, cnt, E);
    k_scan<<<1, 1024, 0, stream>>>(cnt, off, cur, N);
    k_fill<<<eblocks, TB, 0, stream>>>(src, dst, cur, srt, E);

    int aggblocks = (N * 64 + TB - 1) / TB;   // one wave (64 lanes) per node
    int nblocks = (N + TB - 1) / TB;

    // Layer 1
    k_agg<<<aggblocks, TB, 0, stream>>>(x, srt, off, cnt, agg, N);
    k_gemm1<<<dim3(nblocks, 2), TB, 0, stream>>>(agg, x, Wl1, Wr1, b1, h, N);

    // Layer 2
    k_agg<<<aggblocks, TB, 0, stream>>>(h, srt, off, cnt, agg, N);
    k_gemm2<<<nblocks, TB, 0, stream>>>(agg, h, Wl2, Wr2, b2, out, N);
}

// Round 3
// 585.620 us; speedup vs baseline: 1.1031x; 1.0858x over previous
//
#include <hip/hip_runtime.h>
#include <hip/hip_bf16.h>

#define N_FEAT 128
#define N_HID  128
#define N_CLASS 40

// ---------------------------------------------------------------------------
// CSR build: count degrees
// ---------------------------------------------------------------------------
__global__ void k_count(const int* __restrict__ dst, int* __restrict__ cnt, int E) {
    int e = blockIdx.x * blockDim.x + threadIdx.x;
    if (e < E) atomicAdd(&cnt[dst[e]], 1);
}

// ---------------------------------------------------------------------------
// Single-block exclusive prefix scan over cnt[0..n) -> off[0..n], cur copy.
// ---------------------------------------------------------------------------
__global__ __launch_bounds__(1024) void k_scan(const int* __restrict__ cnt,
                                               int* __restrict__ off,
                                               int* __restrict__ cur, int n) {
    const int tid = threadIdx.x;
    const int lane = tid & 63;
    const int wid = tid >> 6;              // 16 waves
    __shared__ int wsum[16];
    __shared__ int carry;
    if (tid == 0) carry = 0;
    __syncthreads();
    for (int base = 0; base < n; base += 1024) {
        int i = base + tid;
        int v = (i < n) ? cnt[i] : 0;
        int inc = v;
        #pragma unroll
        for (int s = 1; s < 64; s <<= 1) {
            int t = __shfl_up(inc, s);
            if (lane >= s) inc += t;
        }
        if (lane == 63) wsum[wid] = inc;
        __syncthreads();
        if (wid == 0) {
            int w = (lane < 16) ? wsum[lane] : 0;
            #pragma unroll
            for (int s = 1; s < 16; s <<= 1) {
                int t = __shfl_up(w, s);
                if (lane >= s) w += t;
            }
            if (lane < 16) wsum[lane] = w;  // inclusive wave sums
        }
        __syncthreads();
        int wbase = (wid > 0) ? wsum[wid - 1] : 0;
        int exc = carry + wbase + inc - v;  // exclusive prefix
        if (i < n) { off[i] = exc; cur[i] = exc; }
        int chunk_total = wsum[15];
        __syncthreads();
        if (tid == 0) carry += chunk_total;
        __syncthreads();
    }
    if (tid == 0) off[n] = carry;           // == E
}

// ---------------------------------------------------------------------------
// CSR build: scatter src ids into per-dst buckets
// ---------------------------------------------------------------------------
__global__ void k_fill(const int* __restrict__ src, const int* __restrict__ dst,
                       int* __restrict__ cur, int* __restrict__ srt, int E) {
    int e = blockIdx.x * blockDim.x + threadIdx.x;
    if (e < E) {
        int p = atomicAdd(&cur[dst[e]], 1);
        srt[p] = src[e];
    }
}

// ---------------------------------------------------------------------------
// Mean aggregation: one wave per node, lane holds 2 features (float2).
// ---------------------------------------------------------------------------
__global__ __launch_bounds__(256) void k_agg(const float* __restrict__ feat,
                                             const int* __restrict__ srt,
                                             const int* __restrict__ off,
                                             const int* __restrict__ cnt,
                                             float* __restrict__ out, int n_nodes) {
    int wave = (blockIdx.x * blockDim.x + threadIdx.x) >> 6;
    int lane = threadIdx.x & 63;
    if (wave >= n_nodes) return;
    int beg = off[wave];
    int end = off[wave + 1];
    float2 acc = make_float2(0.f, 0.f);
    for (int e = beg; e < end; ++e) {
        int s = srt[e];
        const float2* row = (const float2*)(feat + (size_t)s * N_FEAT);
        float2 v = row[lane];
        acc.x += v.x;
        acc.y += v.y;
    }
    int c = cnt[wave];
    float inv = 1.0f / (float)(c > 1 ? c : 1);
    acc.x *= inv;
    acc.y *= inv;
    ((float2*)(out + (size_t)wave * N_FEAT))[lane] = acc;
}

__device__ __forceinline__ float4 relu4(float4 v) {
    float4 o;
    o.x = fmaxf(v.x, 0.f); o.y = fmaxf(v.y, 0.f);
    o.z = fmaxf(v.z, 0.f); o.w = fmaxf(v.w, 0.f);
    return o;
}

// One fused A-step into a named float4 accumulator (registers guaranteed —
// R1/R2 showed float acc[64] alloca is never promoted: VGPR=44-48 + scratch).
#define FMA1(ACC, J) \
    ACC.x = fmaf(av, wl[(J)+0], fmaf(xv, wr[(J)+0], ACC.x)); \
    ACC.y = fmaf(av, wl[(J)+1], fmaf(xv, wr[(J)+1], ACC.y)); \
    ACC.z = fmaf(av, wl[(J)+2], fmaf(xv, wr[(J)+2], ACC.z)); \
    ACC.w = fmaf(av, wl[(J)+3], fmaf(xv, wr[(J)+3], ACC.w));

// ---------------------------------------------------------------------------
// Layer 1: h = relu(agg@Wl + x@Wr + b). Thread = node, 32 cols per y-block
// (8 named float4 accs). grid = (ceil(N/256), 4) -> 784 blocks for occupancy.
// Weight addresses are wave-uniform -> scalar s_loads.
// ---------------------------------------------------------------------------
__global__ __launch_bounds__(256, 4) void k_gemm1(const float* __restrict__ agg,
                                                  const float* __restrict__ x,
                                                  const float* __restrict__ Wl,
                                                  const float* __restrict__ Wr,
                                                  const float* __restrict__ b,
                                                  float* __restrict__ h, int n_nodes) {
    int n = blockIdx.x * 256 + threadIdx.x;
    int cbase = blockIdx.y * 32;
    if (n >= n_nodes) return;
    const float4* bb = (const float4*)(b + cbase);
    float4 acc0 = bb[0], acc1 = bb[1], acc2 = bb[2], acc3 = bb[3],
           acc4 = bb[4], acc5 = bb[5], acc6 = bb[6], acc7 = bb[7];
    const float4* arow = (const float4*)(agg + (size_t)n * N_FEAT);
    const float4* xrow = (const float4*)(x + (size_t)n * N_FEAT);
    const float* wlp = Wl + cbase;
    const float* wrp = Wr + cbase;

    #define KSUB1(AV, XV, K) { \
        float av = (AV); float xv = (XV); \
        const float* wl = wlp + (size_t)(K) * N_HID; \
        const float* wr = wrp + (size_t)(K) * N_HID; \
        FMA1(acc0, 0)  FMA1(acc1, 4)  FMA1(acc2, 8)  FMA1(acc3, 12) \
        FMA1(acc4, 16) FMA1(acc5, 20) FMA1(acc6, 24) FMA1(acc7, 28) }

    for (int k4 = 0; k4 < N_FEAT / 4; ++k4) {
        float4 va = arow[k4];
        float4 vx = xrow[k4];
        KSUB1(va.x, vx.x, k4 * 4 + 0)
        KSUB1(va.y, vx.y, k4 * 4 + 1)
        KSUB1(va.z, vx.z, k4 * 4 + 2)
        KSUB1(va.w, vx.w, k4 * 4 + 3)
    }
    float4* hrow = (float4*)(h + (size_t)n * N_HID + cbase);
    hrow[0] = relu4(acc0); hrow[1] = relu4(acc1);
    hrow[2] = relu4(acc2); hrow[3] = relu4(acc3);
    hrow[4] = relu4(acc4); hrow[5] = relu4(acc5);
    hrow[6] = relu4(acc6); hrow[7] = relu4(acc7);
    #undef KSUB1
}

// ---------------------------------------------------------------------------
// Layer 2: out = agg2@Wl2 + h@Wr2 + b2. Thread = node, 20 cols per y-block
// (5 named float4 accs). grid = (ceil(N/256), 2).
// ---------------------------------------------------------------------------
__global__ __launch_bounds__(256, 4) void k_gemm2(const float* __restrict__ agg2,
                                                  const float* __restrict__ h,
                                                  const float* __restrict__ Wl,
                                                  const float* __restrict__ Wr,
                                                  const float* __restrict__ b,
                                                  float* __restrict__ outp, int n_nodes) {
    int n = blockIdx.x * 256 + threadIdx.x;
    int cbase = blockIdx.y * 20;
    if (n >= n_nodes) return;
    const float4* bb = (const float4*)(b + cbase);
    float4 acc0 = bb[0], acc1 = bb[1], acc2 = bb[2], acc3 = bb[3], acc4 = bb[4];
    const float4* arow = (const float4*)(agg2 + (size_t)n * N_HID);
    const float4* hrow = (const float4*)(h + (size_t)n * N_HID);
    const float* wlp = Wl + cbase;
    const float* wrp = Wr + cbase;

    #define KSUB2(AV, XV, K) { \
        float av = (AV); float xv = (XV); \
        const float* wl = wlp + (size_t)(K) * N_CLASS; \
        const float* wr = wrp + (size_t)(K) * N_CLASS; \
        FMA1(acc0, 0) FMA1(acc1, 4) FMA1(acc2, 8) FMA1(acc3, 12) FMA1(acc4, 16) }

    for (int k4 = 0; k4 < N_HID / 4; ++k4) {
        float4 va = arow[k4];
        float4 vh = hrow[k4];
        KSUB2(va.x, vh.x, k4 * 4 + 0)
        KSUB2(va.y, vh.y, k4 * 4 + 1)
        KSUB2(va.z, vh.z, k4 * 4 + 2)
        KSUB2(va.w, vh.w, k4 * 4 + 3)
    }
    float4* orow = (float4*)(outp + (size_t)n * N_CLASS + cbase);
    orow[0] = acc0; orow[1] = acc1; orow[2] = acc2; orow[3] = acc3; orow[4] = acc4;
    #undef KSUB2
}

extern "C" void kernel_launch(void* const* d_in, const int* in_sizes, int n_in,
                              void* d_out, int out_size, void* d_ws, size_t ws_size,
                              hipStream_t stream) {
    const float* x   = (const float*)d_in[0];
    const int*   ei  = (const int*)d_in[1];   // [2][E] int32: row0=src, row1=dst
    const float* Wl1 = (const float*)d_in[2];
    const float* Wr1 = (const float*)d_in[3];
    const float* b1  = (const float*)d_in[4];
    const float* Wl2 = (const float*)d_in[5];
    const float* Wr2 = (const float*)d_in[6];
    const float* b2  = (const float*)d_in[7];
    float* out = (float*)d_out;

    const int N = in_sizes[0] / N_FEAT;       // 50000
    const int E = in_sizes[1] / 2;            // 800000
    const int* src = ei;
    const int* dst = ei + E;

    float* agg = (float*)d_ws;                       // N*128 fp32 (reused for agg2)
    float* h   = agg + (size_t)N * N_FEAT;           // N*128 fp32
    int*   cnt = (int*)(h + (size_t)N * N_HID);      // N
    int*   off = cnt + N;                            // N+1
    int*   cur = off + N + 1;                        // N
    int*   srt = cur + N;                            // E

    hipMemsetAsync(cnt, 0, (size_t)N * sizeof(int), stream);

    const int TB = 256;
    int eblocks = (E + TB - 1) / TB;
    k_count<<<eblocks, TB, 0, stream>>>(dst, cnt, E);
    k_scan<<<1, 1024, 0, stream>>>(cnt, off, cur, N);
    k_fill<<<eblocks, TB, 0, stream>>>(src, dst, cur, srt, E);

    int aggblocks = (N * 64 + TB - 1) / TB;   // one wave (64 lanes) per node
    int nblocks = (N + TB - 1) / TB;

    // Layer 1
    k_agg<<<aggblocks, TB, 0, stream>>>(x, srt, off, cnt, agg, N);
    k_gemm1<<<dim3(nblocks, 4), TB, 0, stream>>>(agg, x, Wl1, Wr1, b1, h, N);

    // Layer 2
    k_agg<<<aggblocks, TB, 0, stream>>>(h, srt, off, cnt, agg, N);
    k_gemm2<<<dim3(nblocks, 2), TB, 0, stream>>>(agg, h, Wl2, Wr2, b2, out, N);
}